// Round 2
// baseline (399.383 us; speedup 1.0000x reference)
//
#include <hip/hip_runtime.h>
#include <math.h>

// WeightedLogits forward: B=1024 rows, K=66560 cols, f32.
// Pass A: s = sum(exp(l)), g = max(l*exp(l))  [diag inclusion in g is harmless:
//         M only needs to be an upper bound for the LSE shift]
// Pass B: z = sum(exp(u - M)), u = (k==r)? d : c*l*exp(l),  c = (K-1)/(s-exp(d))
// row_loss = M + log(z) - d ;  out = mean(row_loss)

#define TPB 512
#define NWAVES (TPB / 64)

__global__ __launch_bounds__(TPB) void wl_row_kernel(const float* __restrict__ logits,
                                                     float* __restrict__ row_loss,
                                                     int B, int K) {
    __shared__ float sh_s[NWAVES];
    __shared__ float sh_g[NWAVES];
    __shared__ float sh_bc[3];   // c, M, d

    const int tid  = threadIdx.x;
    const int lane = tid & 63;
    const int wid  = tid >> 6;
    const int K4   = K >> 2;

    for (int r = blockIdx.x; r < B; r += gridDim.x) {
        const float4* __restrict__ row4 = (const float4*)(logits + (size_t)r * (size_t)K);

        // ---- Pass A: sum(exp) and max(l*exp(l)) ----
        float s = 0.0f;
        float g = -INFINITY;
        for (int i = tid; i < K4; i += TPB) {
            float4 v = row4[i];
            float e0 = __expf(v.x), e1 = __expf(v.y), e2 = __expf(v.z), e3 = __expf(v.w);
            s += (e0 + e1) + (e2 + e3);
            g = fmaxf(g, fmaxf(fmaxf(v.x * e0, v.y * e1), fmaxf(v.z * e2, v.w * e3)));
        }
        #pragma unroll
        for (int off = 32; off > 0; off >>= 1) {
            s += __shfl_down(s, off);
            g = fmaxf(g, __shfl_down(g, off));
        }
        if (lane == 0) { sh_s[wid] = s; sh_g[wid] = g; }
        __syncthreads();
        if (tid == 0) {
            float st = 0.0f, gt = -INFINITY;
            #pragma unroll
            for (int w = 0; w < NWAVES; ++w) { st += sh_s[w]; gt = fmaxf(gt, sh_g[w]); }
            float d  = logits[(size_t)r * (size_t)K + (size_t)r];
            float ed = __expf(d);
            float neg_mean = (st - ed) / (float)(K - 1);
            float c = 1.0f / neg_mean;
            float M = fmaxf(d, c * gt);   // upper bound on max(u) — LSE shift-invariant
            sh_bc[0] = c; sh_bc[1] = M; sh_bc[2] = d;
        }
        __syncthreads();
        const float c = sh_bc[0];
        const float M = sh_bc[1];
        const float d = sh_bc[2];

        // ---- Pass B: z = sum(exp(u - M)) ----
        float z = 0.0f;
        for (int i = tid; i < K4; i += TPB) {
            float4 v = row4[i];
            const int col = i << 2;
            float e0 = __expf(v.x), e1 = __expf(v.y), e2 = __expf(v.z), e3 = __expf(v.w);
            float u0 = fmaf(c, v.x * e0, -M);
            float u1 = fmaf(c, v.y * e1, -M);
            float u2 = fmaf(c, v.z * e2, -M);
            float u3 = fmaf(c, v.w * e3, -M);
            if (col     == r) u0 = d - M;   // positive pair keeps raw logit
            if (col + 1 == r) u1 = d - M;
            if (col + 2 == r) u2 = d - M;
            if (col + 3 == r) u3 = d - M;
            z += (__expf(u0) + __expf(u1)) + (__expf(u2) + __expf(u3));
        }
        #pragma unroll
        for (int off = 32; off > 0; off >>= 1) z += __shfl_down(z, off);
        if (lane == 0) sh_s[wid] = z;
        __syncthreads();
        if (tid == 0) {
            float zt = 0.0f;
            #pragma unroll
            for (int w = 0; w < NWAVES; ++w) zt += sh_s[w];
            row_loss[r] = M + logf(zt) - d;
        }
        __syncthreads();   // protect shared reuse for next row
    }
}

__global__ __launch_bounds__(256) void wl_final_kernel(const float* __restrict__ row_loss,
                                                       float* __restrict__ out, int B) {
    __shared__ float sh[4];
    const int tid = threadIdx.x;
    float s = 0.0f;
    for (int i = tid; i < B; i += 256) s += row_loss[i];
    #pragma unroll
    for (int off = 32; off > 0; off >>= 1) s += __shfl_down(s, off);
    const int lane = tid & 63, wid = tid >> 6;
    if (lane == 0) sh[wid] = s;
    __syncthreads();
    if (tid == 0) {
        out[0] = (sh[0] + sh[1] + sh[2] + sh[3]) / (float)B;
    }
}

extern "C" void kernel_launch(void* const* d_in, const int* in_sizes, int n_in,
                              void* d_out, int out_size, void* d_ws, size_t ws_size,
                              hipStream_t stream) {
    const float* logits = (const float*)d_in[0];
    const int B = 1024;                 // fixed by the problem (batch_size)
    const int K = in_sizes[0] / B;      // 66560
    float* ws  = (float*)d_ws;          // B row losses
    float* out = (float*)d_out;

    // 512 blocks x 512 threads: each block owns rows {b, b+512} sequentially.
    // Concurrent row working-set = 512 * 266 KB = 136 MB < 256 MB L3, so the
    // second pass re-reads from Infinity Cache instead of HBM.
    wl_row_kernel<<<512, TPB, 0, stream>>>(logits, ws, B, K);
    wl_final_kernel<<<1, 256, 0, stream>>>(ws, out, B);
}

// Round 6
// 382.549 us; speedup vs baseline: 1.0440x; 1.0440x over previous
//
#include <hip/hip_runtime.h>
#include <hip/hip_fp16.h>
#include <math.h>

// WeightedLogits forward: B=1024 rows, K=66560 cols, f32. Single HBM pass.
// Pass A (global->LDS): s = sum(exp(l)) [f32], g = max(l*exp(l)) [f32],
//                       store g_k = l_k*exp(l_k) as fp16 in LDS (130 KB).
// c = (K-1)/(s - exp(d)),  M = max(d, c*g)  (exact max of u, f32).
// Pass B (LDS only): z = sum(exp(c*g_k - M)); terms with u > -34 are
//   recomputed from the f32 global value (rare, L2-hot) so the dominant
//   exp() terms carry f32 precision; diag term uses u = d - M exactly.
// row_loss = M + log(z) - d ; out = mean(row_loss).

#define TPB 1024
#define NWAVES (TPB / 64)
#define KMAX 66560

__global__ __launch_bounds__(TPB, 1) void wl_row_kernel(const float* __restrict__ logits,
                                                        float* __restrict__ row_loss,
                                                        int B, int K) {
    __shared__ __align__(16) __half g16[KMAX];   // 133,120 B
    __shared__ float sh_s[NWAVES];
    __shared__ float sh_g[NWAVES];
    __shared__ float sh_bc[3];   // c, M, d

    const int tid  = threadIdx.x;
    const int lane = tid & 63;
    const int wid  = tid >> 6;
    const int K4   = K >> 2;

    for (int r = blockIdx.x; r < B; r += gridDim.x) {
        const float* __restrict__ row  = logits + (size_t)r * (size_t)K;
        const float4* __restrict__ row4 = (const float4*)row;

        // ---- Pass A: stream HBM once; f32 sum/max; fp16 g -> LDS ----
        float s = 0.0f;
        float g = -INFINITY;
        for (int i = tid; i < K4; i += TPB) {
            float4 v = row4[i];
            float e0 = __expf(v.x), e1 = __expf(v.y), e2 = __expf(v.z), e3 = __expf(v.w);
            float g0 = v.x * e0, g1 = v.y * e1, g2 = v.z * e2, g3 = v.w * e3;
            s += (e0 + e1) + (e2 + e3);
            g = fmaxf(g, fmaxf(fmaxf(g0, g1), fmaxf(g2, g3)));
            union { __half2 h[2]; float2 f; } pk;
            pk.h[0] = __floats2half2_rn(g0, g1);
            pk.h[1] = __floats2half2_rn(g2, g3);
            ((float2*)g16)[i] = pk.f;            // ds_write_b64, conflict-free
        }
        #pragma unroll
        for (int off = 32; off > 0; off >>= 1) {
            s += __shfl_down(s, off);
            g = fmaxf(g, __shfl_down(g, off));
        }
        if (lane == 0) { sh_s[wid] = s; sh_g[wid] = g; }
        __syncthreads();
        if (tid == 0) {
            float st = 0.0f, gt = -INFINITY;
            #pragma unroll
            for (int w = 0; w < NWAVES; ++w) { st += sh_s[w]; gt = fmaxf(gt, sh_g[w]); }
            float d  = row[r];
            float ed = __expf(d);
            float neg_mean = (st - ed) / (float)(K - 1);
            float c = 1.0f / neg_mean;
            float M = fmaxf(d, c * gt);          // exact max of u (f32)
            sh_bc[0] = c; sh_bc[1] = M; sh_bc[2] = d;
        }
        __syncthreads();
        const float c = sh_bc[0];
        const float M = sh_bc[1];
        const float d = sh_bc[2];

        // ---- Pass B: LDS only ----
        float z = 0.0f;
        for (int i = tid; i < K4; i += TPB) {
            union { __half2 h[2]; float2 f; } pk;
            pk.f = ((const float2*)g16)[i];
            float2 g01 = __half22float2(pk.h[0]);
            float2 g23 = __half22float2(pk.h[1]);
            float u0 = fmaf(c, g01.x, -M);
            float u1 = fmaf(c, g01.y, -M);
            float u2 = fmaf(c, g23.x, -M);
            float u3 = fmaf(c, g23.y, -M);
            const int col = i << 2;
            // f32 refinement for terms that matter in log-sum-exp (rare, L2-hot)
            if (u0 > -34.0f) { float lf = row[col    ]; u0 = fmaf(c, lf * __expf(lf), -M); }
            if (u1 > -34.0f) { float lf = row[col + 1]; u1 = fmaf(c, lf * __expf(lf), -M); }
            if (u2 > -34.0f) { float lf = row[col + 2]; u2 = fmaf(c, lf * __expf(lf), -M); }
            if (u3 > -34.0f) { float lf = row[col + 3]; u3 = fmaf(c, lf * __expf(lf), -M); }
            if (col     == r) u0 = d - M;        // positive pair keeps raw logit
            if (col + 1 == r) u1 = d - M;
            if (col + 2 == r) u2 = d - M;
            if (col + 3 == r) u3 = d - M;
            z += (__expf(u0) + __expf(u1)) + (__expf(u2) + __expf(u3));
        }
        #pragma unroll
        for (int off = 32; off > 0; off >>= 1) z += __shfl_down(z, off);
        if (lane == 0) sh_s[wid] = z;
        __syncthreads();
        if (tid == 0) {
            float zt = 0.0f;
            #pragma unroll
            for (int w = 0; w < NWAVES; ++w) zt += sh_s[w];
            row_loss[r] = M + logf(zt) - d;
        }
        __syncthreads();   // protect shared reuse for next row
    }
}

__global__ __launch_bounds__(256) void wl_final_kernel(const float* __restrict__ row_loss,
                                                       float* __restrict__ out, int B) {
    __shared__ float sh[4];
    const int tid = threadIdx.x;
    float s = 0.0f;
    for (int i = tid; i < B; i += 256) s += row_loss[i];
    #pragma unroll
    for (int off = 32; off > 0; off >>= 1) s += __shfl_down(s, off);
    const int lane = tid & 63, wid = tid >> 6;
    if (lane == 0) sh[wid] = s;
    __syncthreads();
    if (tid == 0) {
        out[0] = (sh[0] + sh[1] + sh[2] + sh[3]) / (float)B;
    }
}

extern "C" void kernel_launch(void* const* d_in, const int* in_sizes, int n_in,
                              void* d_out, int out_size, void* d_ws, size_t ws_size,
                              hipStream_t stream) {
    const float* logits = (const float*)d_in[0];
    const int B = 1024;                 // fixed by the problem (batch_size)
    const int K = in_sizes[0] / B;      // 66560
    float* ws  = (float*)d_ws;          // B row losses
    float* out = (float*)d_out;

    // One block per row; 130 KB LDS -> 1 block/CU, 16 waves. Single HBM pass.
    wl_row_kernel<<<B, TPB, 0, stream>>>(logits, ws, B, K);
    wl_final_kernel<<<1, 256, 0, stream>>>(ws, out, B);
}